// Round 7
// baseline (220.483 us; speedup 1.0000x reference)
//
#include <hip/hip_runtime.h>
#include <hip/hip_bf16.h>

// BagOfWords: input [1024, 512] int32 tokens in [0, 50257).
// Output [1024, 50256] float32: per-row histogram, vocab bin 0 dropped.
//
// Round 7 = isolation experiment. Structure: (1) my own streaming zero-fill
// of d_out (grid-stride float4 stores), (2) scatter kernel: one thread per
// token, global atomicAdd(+1.0f). Purpose: measure whether the 4x HBM write
// amplification seen on every rocclr fillBufferAligned (WRITE_SIZE=804096 KB
// for a 201024 KB buffer, every round) also applies to a plain store kernel.
// R2/R5/R6 showed dur_us is invariant (~197) to block structure / LDS layout /
// barrier count, so the store path is the suspect.

#define BATCH 1024
#define SEQ 512
#define VOCAB 50257
#define OUT_COLS (VOCAB - 1)   // 50256
#define OUT_ELEMS ((size_t)BATCH * OUT_COLS)        // 51,462,144 (div by 4)
#define OUT_F4 (OUT_ELEMS / 4)                      // 12,865,536

typedef float vfloat4 __attribute__((ext_vector_type(4)));

__global__ __launch_bounds__(256) void bow_zero_kernel(float* __restrict__ out) {
    const size_t stride = (size_t)gridDim.x * 256;
    vfloat4* o4 = (vfloat4*)out;
    const vfloat4 z = {0.f, 0.f, 0.f, 0.f};
    for (size_t i = (size_t)blockIdx.x * 256 + threadIdx.x; i < OUT_F4; i += stride)
        o4[i] = z;
}

__global__ __launch_bounds__(256) void bow_scatter_kernel(
    const int* __restrict__ tokens, float* __restrict__ out) {
    int idx = blockIdx.x * 256 + threadIdx.x;   // one thread per token
    int b = idx >> 9;                            // idx / SEQ
    int tok = tokens[idx];
    if (tok != 0) {
        atomicAdd(&out[(size_t)b * OUT_COLS + (tok - 1)], 1.0f);
    }
}

extern "C" void kernel_launch(void* const* d_in, const int* in_sizes, int n_in,
                              void* d_out, int out_size, void* d_ws, size_t ws_size,
                              hipStream_t stream) {
    const int* tokens = (const int*)d_in[0];
    float* out = (float*)d_out;

    // Streaming zero: 8192 blocks x 256 threads, ~6 float4 stores each.
    bow_zero_kernel<<<8192, 256, 0, stream>>>(out);

    // Scatter: 524288 tokens, one thread each -> 2048 blocks.
    bow_scatter_kernel<<<(BATCH * SEQ) / 256, 256, 0, stream>>>(tokens, out);
}